// Round 10
// baseline (386.751 us; speedup 1.0000x reference)
//
#include <hip/hip_runtime.h>
#include <hip/hip_fp16.h>
#include <stdint.h>

constexpr int N_NODES = 50000;
constexpr int N_EDGES = 800000;
constexpr int HD      = 128;
constexpr int NREL    = 8;
constexpr int NBUCK   = N_NODES * NREL;   // 400000 (dst,etype) buckets

typedef unsigned short ushortT;
using bf16x8 = __attribute__((ext_vector_type(8))) short;
using f32x4  = __attribute__((ext_vector_type(4))) float;

__device__ __forceinline__ float b2f(uint32_t lo16){
  uint32_t x = lo16 << 16; float f; __builtin_memcpy(&f,&x,4); return f;
}
__device__ __forceinline__ uint16_t f2b(float f){
  uint32_t x; __builtin_memcpy(&x,&f,4);
  uint32_t r = (x + 0x7FFFu + ((x>>16)&1u)) >> 16;
  return (uint16_t)r;
}

// ---------------- CSR build over (dst*8+etype) buckets ----------------
__global__ void k_hist(const int* __restrict__ dst, const int* __restrict__ et,
                       int* __restrict__ deg){
  int i = blockIdx.x*blockDim.x + threadIdx.x;
  if(i<N_EDGES) atomicAdd(&deg[dst[i]*NREL + et[i]],1);
}

__global__ void k_scan1(const int* __restrict__ in, int* __restrict__ out,
                        int* __restrict__ part, int n){
  __shared__ int sm[256];
  int t = threadIdx.x; int i = blockIdx.x*256+t;
  int v = (i<n)? in[i] : 0;
  sm[t]=v; __syncthreads();
  for(int off=1; off<256; off<<=1){
    int x = (t>=off)? sm[t-off] : 0;
    __syncthreads();
    sm[t]+=x;
    __syncthreads();
  }
  if(i<n) out[i]=sm[t]-v;       // exclusive within block
  if(t==255) part[blockIdx.x]=sm[255];
}

// single-block chunked scan of the partials
__global__ void k_scanmid(int* __restrict__ part, int n){
  __shared__ int sm[256];
  __shared__ int carry;
  int t=threadIdx.x;
  if(t==0) carry=0;
  __syncthreads();
  for(int base=0; base<n; base+=256){
    int i=base+t;
    int v=(i<n)? part[i] : 0;
    sm[t]=v; __syncthreads();
    for(int off=1; off<256; off<<=1){
      int x=(t>=off)? sm[t-off] : 0;
      __syncthreads();
      sm[t]+=x;
      __syncthreads();
    }
    int tot = sm[255];
    if(i<n) part[i]=sm[t]-v+carry;
    __syncthreads();
    if(t==0) carry += tot;
    __syncthreads();
  }
}

// edge record: src in low 16 bits, fp16 weight in high 16 bits (4B total)
// bucket base = offs[b] (block-local) + part[b>>8]
__global__ void k_scatter(const int* __restrict__ src, const int* __restrict__ et,
                          const float* __restrict__ w, const int* __restrict__ dst,
                          const int* __restrict__ offs, const int* __restrict__ part,
                          int* __restrict__ cur, uint32_t* __restrict__ es){
  int i = blockIdx.x*blockDim.x + threadIdx.x;
  if(i<N_EDGES){
    int b = dst[i]*NREL + et[i];
    int pos = offs[b] + part[b>>8] + atomicAdd(&cur[b],1);
    __half h = __float2half(w[i]);
    ushortT hb; __builtin_memcpy(&hb,&h,2);
    es[pos] = (uint32_t)(src[i] & 0xFFFF) | ((uint32_t)hb << 16);
  }
}

// ---------------- fused prep: f2b table convert + relation weights --------
constexpr int F2B_BLOCKS = (N_NODES*HD/4 + 255)/256;   // 6250
__global__ void k_prep(const float* __restrict__ feat,
                       const float* __restrict__ comp1, const float* __restrict__ V1,
                       const float* __restrict__ comp2, const float* __restrict__ V2,
                       ushortT* __restrict__ xb,
                       ushortT* __restrict__ Wt1, ushortT* __restrict__ Wt2){
  if(blockIdx.x < F2B_BLOCKS){
    int i = blockIdx.x*256 + threadIdx.x;
    if(i < N_NODES*HD/4){
      float4 v = ((const float4*)feat)[i];
      ushort4 o;
      o.x=f2b(v.x); o.y=f2b(v.y); o.z=f2b(v.z); o.w=f2b(v.w);
      ((ushort4*)xb)[i]=o;
    }
  } else {
    int t = (blockIdx.x - F2B_BLOCKS)*256 + threadIdx.x;   // 0..262143
    int layer = t >> 17;
    t &= 131071;
    const float* comp = layer? comp2 : comp1;
    const float* V    = layer? V2    : V1;
    ushortT* Wt       = layer? Wt2   : Wt1;
    int o  = t >> 10;                // 0..127
    int rk = t & 1023;
    int r  = rk >> 7, k = rk & 127;
    float s=0.f;
    #pragma unroll
    for(int b=0;b<NREL;b++) s += comp[r*NREL+b]*V[(b<<14) + k*HD + o];
    Wt[t]=f2b(s);
  }
}

// ---------------- fully-fused RGCN layer ----------------
// Block = 512 threads = 32 lane-quarters = 32 nodes.
// Phase 1 (no barriers): each quarter gathers its node's 8 (dst,r) buckets,
//   relations in 2 groups of 4 INDEPENDENT chains (4-way MLP), results packed
//   to 8 per-relation LDS tiles [32][136].
// Phase 2 (one barrier): per wave, 64 unrolled MFMAs: acc += T[r] @ W_r,
//   B-fragments straight from L2-hot Wt; single output write.
constexpr int BN2 = 32, LDK = 136;   // 272B row: 2-way bank alias (free)
__global__ void __launch_bounds__(512)
k_fused(const ushortT* __restrict__ xb,   // [N][128] bf16 gather table
        const ushortT* __restrict__ Wt,   // [128][1024] bf16 (o-major)
        const int* __restrict__ offs, const int* __restrict__ part,
        const int* __restrict__ deg,
        const uint32_t* __restrict__ es,  // packed (src u16, w fp16)
        const float* __restrict__ bias,
        float* __restrict__ outF,         // layer2: f32 out (or null)
        ushortT* __restrict__ outB,       // layer1: bf16 out (or null)
        int relu){
  __shared__ ushortT T[NREL][BN2][LDK];   // 68 KB
  int tid  = threadIdx.x;
  int w    = tid>>6, lane = tid&63;
  int f    = lane&15;                     // feature slice (16B of 256B row)
  int rowq = tid>>4;                      // node-local index 0..31
  int n0   = blockIdx.x*BN2;
  int node = n0 + rowq;

  int beg[8], cnt[8];
  if(node < N_NODES){
    int b0 = node*NREL;
    int base = part[b0>>8];               // all 8 buckets share a scan-block
    #pragma unroll
    for(int r=0;r<8;r++){ beg[r] = offs[b0+r] + base; cnt[r] = deg[b0+r]; }
  } else {
    #pragma unroll
    for(int r=0;r<8;r++){ beg[r]=0; cnt[r]=0; }
  }

  // ---- phase 1: gather (barrier-free, 4 independent chains per group) ----
  #pragma unroll
  for(int g=0; g<2; ++g){
    float a[4][8] = {};
    int mc = 0;
    #pragma unroll
    for(int rr=0;rr<4;rr++){ int c = cnt[g*4+rr]; mc = (c>mc)? c : mc; }
    for(int j=0;j<mc;j++){
      #pragma unroll
      for(int rr=0;rr<4;rr++){
        int r = g*4+rr;
        if(j < cnt[r]){
          uint32_t ce = es[beg[r]+j];
          ushortT hb = (ushortT)(ce >> 16);
          __half h; __builtin_memcpy(&h,&hb,2);
          float wv = __half2float(h);
          bf16x8 v = *(const bf16x8*)&xb[(size_t)(ce & 0xFFFFu)*HD + f*8];
          #pragma unroll
          for(int t=0;t<8;t++) a[rr][t] += wv * b2f((uint16_t)v[t]);
        }
      }
    }
    #pragma unroll
    for(int rr=0;rr<4;rr++){
      uint32_t pk[4];
      #pragma unroll
      for(int i=0;i<4;i++)
        pk[i] = (uint32_t)f2b(a[rr][2*i]) | ((uint32_t)f2b(a[rr][2*i+1])<<16);
      *(uint4*)&T[g*4+rr][rowq][f*8] = *(uint4*)pk;
    }
  }
  __syncthreads();   // the ONLY barrier

  // ---- phase 2: 64 MFMAs per wave; wave w -> cols w*16..w*16+15 ----
  int l15 = lane&15, lhi = lane>>4;
  f32x4 acc[2] = {};
  #pragma unroll
  for(int r=0;r<NREL;r++){
    #pragma unroll
    for(int kk=0;kk<4;kk++){
      bf16x8 bfr = *(const bf16x8*)&Wt[(size_t)(w*16 + l15)*1024
                                       + r*HD + kk*32 + lhi*8];
      #pragma unroll
      for(int m=0;m<2;m++){
        bf16x8 af = *(const bf16x8*)&T[r][m*16 + l15][kk*32 + lhi*8];
        acc[m] = __builtin_amdgcn_mfma_f32_16x16x32_bf16(af, bfr, acc[m], 0,0,0);
      }
    }
  }

  // ---- epilogue: D row=lhi*4+j, col=l15 ----
  #pragma unroll
  for(int m=0;m<2;m++){
    #pragma unroll
    for(int j=0;j<4;j++){
      int grow = n0 + m*16 + lhi*4 + j;
      if(grow < N_NODES){
        int col = w*16 + l15;
        float v = acc[m][j] + bias[col];
        if(relu) v = fmaxf(v, 0.f);
        if(outF) outF[(size_t)grow*HD + col] = v;
        else     outB[(size_t)grow*HD + col] = f2b(v);
      }
    }
  }
}

extern "C" void kernel_launch(void* const* d_in, const int* in_sizes, int n_in,
                              void* d_out, int out_size, void* d_ws, size_t ws_size,
                              hipStream_t stream){
  const float* feat  = (const float*)d_in[0];
  const int*   etyp  = (const int*)  d_in[1];
  const float* ew    = (const float*)d_in[2];
  const int*   src   = (const int*)  d_in[3];
  const int*   dst   = (const int*)  d_in[4];
  const float* comp1 = (const float*)d_in[5];
  const float* V1    = (const float*)d_in[6];
  const float* bias1 = (const float*)d_in[7];
  const float* comp2 = (const float*)d_in[8];
  const float* V2    = (const float*)d_in[9];
  const float* bias2 = (const float*)d_in[10];
  float* out = (float*)d_out;

  char* p = (char*)d_ws;
  auto alloc = [&](size_t bytes)->char* {
    char* q = p; p += (bytes + 255) & ~(size_t)255; return q;
  };
  ushortT* Wt1  = (ushortT*)alloc((size_t)HD*NREL*HD*2);      // 256 KB
  ushortT* Wt2  = (ushortT*)alloc((size_t)HD*NREL*HD*2);      // 256 KB
  ushortT* xb   = (ushortT*)alloc((size_t)N_NODES*HD*2);      // 12.8 MB
  ushortT* hmid = (ushortT*)alloc((size_t)N_NODES*HD*2);      // 12.8 MB
  int*   deg   = (int*)  alloc((size_t)NBUCK*4);
  int*   cur   = (int*)  alloc((size_t)NBUCK*4);              // adjacent to deg
  int*   offs  = (int*)  alloc((size_t)NBUCK*4);
  int*   part1 = (int*)  alloc(2048*4);
  uint32_t* es = (uint32_t*)alloc((size_t)N_EDGES*4);         // 3.2 MB

  // ---- CSR build over 400k (dst,etype) buckets ----
  hipMemsetAsync(deg, 0, (size_t)2*NBUCK*4, stream);          // deg + cur
  k_hist<<<(N_EDGES+255)/256,256,0,stream>>>(dst,etyp,deg);
  int nb1 = (NBUCK+255)/256;          // 1563
  k_scan1<<<nb1,256,0,stream>>>(deg,offs,part1,NBUCK);
  k_scanmid<<<1,256,0,stream>>>(part1,nb1);
  k_scatter<<<(N_EDGES+255)/256,256,0,stream>>>(src,etyp,ew,dst,offs,part1,cur,es);

  // ---- fused prep: bf16 table + relation weights (both layers) ----
  k_prep<<<F2B_BLOCKS + 1024, 256, 0, stream>>>(feat,comp1,V1,comp2,V2,xb,Wt1,Wt2);

  int grid = (N_NODES + BN2 - 1)/BN2;   // 1563
  // ---- layer 1 (fused, bf16 out + relu) ----
  k_fused<<<grid,512,0,stream>>>(xb,   Wt1, offs, part1, deg, es, bias1, nullptr, hmid, 1);
  // ---- layer 2 (fused, f32 out) ----
  k_fused<<<grid,512,0,stream>>>(hmid, Wt2, offs, part1, deg, es, bias2, out, nullptr, 0);
}

// Round 11
// 267.883 us; speedup vs baseline: 1.4437x; 1.4437x over previous
//
#include <hip/hip_runtime.h>
#include <hip/hip_fp16.h>
#include <stdint.h>

constexpr int N_NODES = 50000;
constexpr int N_EDGES = 800000;
constexpr int HD      = 128;
constexpr int NREL    = 8;
constexpr int NBUCK   = N_NODES * NREL;   // 400000 (dst,etype) buckets

typedef unsigned short ushortT;
using bf16x8 = __attribute__((ext_vector_type(8))) short;
using f32x4  = __attribute__((ext_vector_type(4))) float;

__device__ __forceinline__ float b2f(uint32_t lo16){
  uint32_t x = lo16 << 16; float f; __builtin_memcpy(&f,&x,4); return f;
}
__device__ __forceinline__ uint16_t f2b(float f){
  uint32_t x; __builtin_memcpy(&x,&f,4);
  uint32_t r = (x + 0x7FFFu + ((x>>16)&1u)) >> 16;
  return (uint16_t)r;
}

// ---------------- CSR build over (dst*8+etype) buckets ----------------
__global__ void k_hist(const int* __restrict__ dst, const int* __restrict__ et,
                       int* __restrict__ deg){
  int i = blockIdx.x*blockDim.x + threadIdx.x;
  if(i<N_EDGES) atomicAdd(&deg[dst[i]*NREL + et[i]],1);
}

__global__ void k_scan1(const int* __restrict__ in, int* __restrict__ out,
                        int* __restrict__ part, int n){
  __shared__ int sm[256];
  int t = threadIdx.x; int i = blockIdx.x*256+t;
  int v = (i<n)? in[i] : 0;
  sm[t]=v; __syncthreads();
  for(int off=1; off<256; off<<=1){
    int x = (t>=off)? sm[t-off] : 0;
    __syncthreads();
    sm[t]+=x;
    __syncthreads();
  }
  if(i<n) out[i]=sm[t]-v;       // exclusive within block
  if(t==255) part[blockIdx.x]=sm[255];
}

// single-block chunked scan of the partials
__global__ void k_scanmid(int* __restrict__ part, int n){
  __shared__ int sm[256];
  __shared__ int carry;
  int t=threadIdx.x;
  if(t==0) carry=0;
  __syncthreads();
  for(int base=0; base<n; base+=256){
    int i=base+t;
    int v=(i<n)? part[i] : 0;
    sm[t]=v; __syncthreads();
    for(int off=1; off<256; off<<=1){
      int x=(t>=off)? sm[t-off] : 0;
      __syncthreads();
      sm[t]+=x;
      __syncthreads();
    }
    int tot = sm[255];
    if(i<n) part[i]=sm[t]-v+carry;
    __syncthreads();
    if(t==0) carry += tot;
    __syncthreads();
  }
}

// edge record: src in low 16 bits, fp16 weight in high 16 bits (4B total)
// bucket base = offs[b] (block-local) + part[b>>8]
__global__ void k_scatter(const int* __restrict__ src, const int* __restrict__ et,
                          const float* __restrict__ w, const int* __restrict__ dst,
                          const int* __restrict__ offs, const int* __restrict__ part,
                          int* __restrict__ cur, uint32_t* __restrict__ es){
  int i = blockIdx.x*blockDim.x + threadIdx.x;
  if(i<N_EDGES){
    int b = dst[i]*NREL + et[i];
    int pos = offs[b] + part[b>>8] + atomicAdd(&cur[b],1);
    __half h = __float2half(w[i]);
    ushortT hb; __builtin_memcpy(&hb,&h,2);
    es[pos] = (uint32_t)(src[i] & 0xFFFF) | ((uint32_t)hb << 16);
  }
}

// ---------------- fused prep: f2b table convert + relation weights --------
constexpr int F2B_BLOCKS = (N_NODES*HD/4 + 255)/256;   // 6250
__global__ void k_prep(const float* __restrict__ feat,
                       const float* __restrict__ comp1, const float* __restrict__ V1,
                       const float* __restrict__ comp2, const float* __restrict__ V2,
                       ushortT* __restrict__ xb,
                       ushortT* __restrict__ Wt1, ushortT* __restrict__ Wt2){
  if(blockIdx.x < F2B_BLOCKS){
    int i = blockIdx.x*256 + threadIdx.x;
    if(i < N_NODES*HD/4){
      float4 v = ((const float4*)feat)[i];
      ushort4 o;
      o.x=f2b(v.x); o.y=f2b(v.y); o.z=f2b(v.z); o.w=f2b(v.w);
      ((ushort4*)xb)[i]=o;
    }
  } else {
    int t = (blockIdx.x - F2B_BLOCKS)*256 + threadIdx.x;   // 0..262143
    int layer = t >> 17;
    t &= 131071;
    const float* comp = layer? comp2 : comp1;
    const float* V    = layer? V2    : V1;
    ushortT* Wt       = layer? Wt2   : Wt1;
    int o  = t >> 10;                // 0..127
    int rk = t & 1023;
    int r  = rk >> 7, k = rk & 127;
    float s=0.f;
    #pragma unroll
    for(int b=0;b<NREL;b++) s += comp[r*NREL+b]*V[(b<<14) + k*HD + o];
    Wt[t]=f2b(s);
  }
}

// ---------------- aggregate-first: 4 buckets per WAVE (round-5 proven) -----
// lane = q*16+f : quarter q owns bucket wave*4+q, lane f covers bytes [f*16,f*16+16)
// Acat[b][128] bf16, b = node*8+r  (== A[node][1024] r-major)
__global__ void __launch_bounds__(256)
k_agg(const ushortT* __restrict__ xb,   // [N][128] bf16 gather table
      const int* __restrict__ offs, const int* __restrict__ part,
      const int* __restrict__ deg,
      const uint32_t* __restrict__ es,  // packed (src u16, w fp16)
      ushortT* __restrict__ Acat){
  int wave = blockIdx.x*4 + (threadIdx.x>>6);
  int lane = threadIdx.x & 63;
  int q = lane >> 4, f = lane & 15;
  int b = wave*4 + q;                   // grid sized exactly: NBUCK/4 waves
  int beg = offs[b] + part[b>>8], cnt = deg[b];
  const uint32_t* ep = es + beg;
  float a[8] = {};
  uint32_t e = 0;
  if(cnt > 0) e = ep[0];                // masked prefetch
  for(int j=0;j<cnt;j++){
    uint32_t ce = e;
    if(j+1 < cnt) e = ep[j+1];          // prefetch next edge while gathering
    ushortT hb = (ushortT)(ce >> 16);
    __half h; __builtin_memcpy(&h,&hb,2);
    float w = __half2float(h);
    int s = (int)(ce & 0xFFFFu);
    bf16x8 v = *(const bf16x8*)&xb[(size_t)s*HD + f*8];
    #pragma unroll
    for(int t=0;t<8;t++) a[t] += w * b2f((uint16_t)v[t]);
  }
  uint32_t pk[4];
  #pragma unroll
  for(int i=0;i<4;i++)
    pk[i] = (uint32_t)f2b(a[2*i]) | ((uint32_t)f2b(a[2*i+1])<<16);
  // wave writes 4 adjacent 256B rows -> 1KB contiguous
  *(uint4*)&Acat[(size_t)b*HD + f*8] = *(uint4*)pk;
}

// ---------------- MFMA GEMM (round-5 proven): out[M][128] = A[M][1024] @ Wt^T --
constexpr int BM=64, BN=128, BK=64, LDKG=72;   // pad: 144B row, 2-way alias (free)
__global__ void __launch_bounds__(256)
k_gemm(const ushortT* __restrict__ A,   // [M][1024] bf16
       const ushortT* __restrict__ Wt,  // [128][1024] bf16 (B^T, o-major)
       const float* __restrict__ bias,
       float* __restrict__ outF,        // layer2 output (f32) or null
       ushortT* __restrict__ outB,      // layer1 output (bf16) or null
       int M, int relu){
  __shared__ ushortT Asm[BM][LDKG];
  __shared__ ushortT Bsm[BN][LDKG];
  int tid = threadIdx.x;
  int wid = tid>>6, lane = tid&63;
  int l15 = lane&15, lhi = lane>>4;
  int row0 = blockIdx.x*BM;
  int wr = (wid>>1)*32, wc = (wid&1)*64;   // wave tile 32x64
  f32x4 acc[2][4] = {};
  for(int kt=0; kt<NREL*HD; kt+=BK){
    #pragma unroll
    for(int q=0;q<2;q++){
      int slot = q*256 + tid;
      int r = slot>>3, kb8 = (slot&7)*8;
      int grow = row0 + r; if(grow >= M) grow = M-1;
      *(bf16x8*)&Asm[r][kb8] = *(const bf16x8*)&A[(size_t)grow*1024 + kt + kb8];
    }
    #pragma unroll
    for(int q=0;q<4;q++){
      int slot = q*256 + tid;
      int c = slot>>3, kb8 = (slot&7)*8;
      *(bf16x8*)&Bsm[c][kb8] = *(const bf16x8*)&Wt[(size_t)c*1024 + kt + kb8];
    }
    __syncthreads();
    #pragma unroll
    for(int kk=0;kk<2;kk++){
      bf16x8 af[2], bfr[4];
      #pragma unroll
      for(int m=0;m<2;m++)  af[m]  = *(const bf16x8*)&Asm[wr + m*16 + l15][kk*32 + lhi*8];
      #pragma unroll
      for(int n=0;n<4;n++)  bfr[n] = *(const bf16x8*)&Bsm[wc + n*16 + l15][kk*32 + lhi*8];
      #pragma unroll
      for(int m=0;m<2;m++)
        #pragma unroll
        for(int n=0;n<4;n++)
          acc[m][n] = __builtin_amdgcn_mfma_f32_16x16x32_bf16(af[m], bfr[n], acc[m][n], 0,0,0);
    }
    __syncthreads();
  }
  #pragma unroll
  for(int m=0;m<2;m++){
    #pragma unroll
    for(int j=0;j<4;j++){
      int grow = row0 + wr + m*16 + lhi*4 + j;
      if(grow < M){
        #pragma unroll
        for(int n=0;n<4;n++){
          int col = wc + n*16 + l15;
          float v = acc[m][n][j] + bias[col];
          if(relu) v = fmaxf(v, 0.f);
          if(outF) outF[(size_t)grow*HD + col] = v;
          else     outB[(size_t)grow*HD + col] = f2b(v);
        }
      }
    }
  }
}

extern "C" void kernel_launch(void* const* d_in, const int* in_sizes, int n_in,
                              void* d_out, int out_size, void* d_ws, size_t ws_size,
                              hipStream_t stream){
  const float* feat  = (const float*)d_in[0];
  const int*   etyp  = (const int*)  d_in[1];
  const float* ew    = (const float*)d_in[2];
  const int*   src   = (const int*)  d_in[3];
  const int*   dst   = (const int*)  d_in[4];
  const float* comp1 = (const float*)d_in[5];
  const float* V1    = (const float*)d_in[6];
  const float* bias1 = (const float*)d_in[7];
  const float* comp2 = (const float*)d_in[8];
  const float* V2    = (const float*)d_in[9];
  const float* bias2 = (const float*)d_in[10];
  float* out = (float*)d_out;

  char* p = (char*)d_ws;
  auto alloc = [&](size_t bytes)->char* {
    char* q = p; p += (bytes + 255) & ~(size_t)255; return q;
  };
  ushortT* Wt1   = (ushortT*)alloc((size_t)HD*NREL*HD*2);        // 256 KB
  ushortT* Wt2   = (ushortT*)alloc((size_t)HD*NREL*HD*2);        // 256 KB
  ushortT* Acat  = (ushortT*)alloc((size_t)NBUCK*HD*2);          // 102.4 MB
  ushortT* xb    = (ushortT*)alloc((size_t)N_NODES*HD*2);        // 12.8 MB
  ushortT* hmid  = (ushortT*)alloc((size_t)N_NODES*HD*2);        // 12.8 MB
  int*   deg   = (int*)  alloc((size_t)NBUCK*4);
  int*   cur   = (int*)  alloc((size_t)NBUCK*4);                 // adjacent to deg
  int*   offs  = (int*)  alloc((size_t)NBUCK*4);
  int*   part1 = (int*)  alloc(2048*4);
  uint32_t* es = (uint32_t*)alloc((size_t)N_EDGES*4);            // 3.2 MB

  // ---- CSR build over 400k (dst,etype) buckets ----
  hipMemsetAsync(deg, 0, (size_t)2*NBUCK*4, stream);             // deg + cur
  k_hist<<<(N_EDGES+255)/256,256,0,stream>>>(dst,etyp,deg);
  int nb1 = (NBUCK+255)/256;          // 1563
  k_scan1<<<nb1,256,0,stream>>>(deg,offs,part1,NBUCK);
  k_scanmid<<<1,256,0,stream>>>(part1,nb1);
  k_scatter<<<(N_EDGES+255)/256,256,0,stream>>>(src,etyp,ew,dst,offs,part1,cur,es);

  // ---- fused prep: bf16 table + relation weights (both layers) ----
  k_prep<<<F2B_BLOCKS + 1024, 256, 0, stream>>>(feat,comp1,V1,comp2,V2,xb,Wt1,Wt2);

  int aggGrid  = NBUCK/16;                 // 25000 blocks: 4 waves x 4 buckets
  int gemmGrid = (N_NODES + BM - 1)/BM;    // 782
  // ---- layer 1 ----
  k_agg<<<aggGrid,256,0,stream>>>(xb,   offs, part1, deg, es, Acat);
  k_gemm<<<gemmGrid,256,0,stream>>>(Acat, Wt1, bias1, nullptr, hmid, N_NODES, 1);
  // ---- layer 2 ----
  k_agg<<<aggGrid,256,0,stream>>>(hmid, offs, part1, deg, es, Acat);
  k_gemm<<<gemmGrid,256,0,stream>>>(Acat, Wt2, bias2, out, nullptr, N_NODES, 0);
}

// Round 12
// 242.505 us; speedup vs baseline: 1.5948x; 1.1046x over previous
//
#include <hip/hip_runtime.h>
#include <hip/hip_fp16.h>
#include <stdint.h>

constexpr int N_NODES = 50000;
constexpr int N_EDGES = 800000;
constexpr int HD      = 128;
constexpr int NREL    = 8;
constexpr int NBUCK   = N_NODES * NREL;   // 400000 (dst,etype) buckets

typedef unsigned short ushortT;
using bf16x8 = __attribute__((ext_vector_type(8))) short;
using f32x4  = __attribute__((ext_vector_type(4))) float;

__device__ __forceinline__ float b2f(uint32_t lo16){
  uint32_t x = lo16 << 16; float f; __builtin_memcpy(&f,&x,4); return f;
}
__device__ __forceinline__ uint16_t f2b(float f){
  uint32_t x; __builtin_memcpy(&x,&f,4);
  uint32_t r = (x + 0x7FFFu + ((x>>16)&1u)) >> 16;
  return (uint16_t)r;
}

// ---------------- fused: histogram(+position) | f2b | relw  ----------------
// role A (3125 blocks): deg histogram, per-edge within-bucket position
// role B (6250 blocks): features f32 -> bf16
// role C (1024 blocks): Wt[o][r*128+k] = sum_b comp[r,b] V[b,k,o], both layers
constexpr int H_BLOCKS   = (N_EDGES + 255)/256;        // 3125
constexpr int F2B_BLOCKS = (N_NODES*HD/4 + 255)/256;   // 6250
__global__ void k_histprep(const int* __restrict__ dst, const int* __restrict__ et,
                           int* __restrict__ deg, int* __restrict__ pos,
                           const float* __restrict__ feat,
                           const float* __restrict__ comp1, const float* __restrict__ V1,
                           const float* __restrict__ comp2, const float* __restrict__ V2,
                           ushortT* __restrict__ xb,
                           ushortT* __restrict__ Wt1, ushortT* __restrict__ Wt2){
  if(blockIdx.x < H_BLOCKS){
    int i = blockIdx.x*256 + threadIdx.x;
    if(i<N_EDGES) pos[i] = atomicAdd(&deg[dst[i]*NREL + et[i]],1);
  } else if(blockIdx.x < H_BLOCKS + F2B_BLOCKS){
    int i = (blockIdx.x - H_BLOCKS)*256 + threadIdx.x;
    if(i < N_NODES*HD/4){
      float4 v = ((const float4*)feat)[i];
      ushort4 o;
      o.x=f2b(v.x); o.y=f2b(v.y); o.z=f2b(v.z); o.w=f2b(v.w);
      ((ushort4*)xb)[i]=o;
    }
  } else {
    int t = (blockIdx.x - H_BLOCKS - F2B_BLOCKS)*256 + threadIdx.x; // 0..262143
    int layer = t >> 17;
    t &= 131071;
    const float* comp = layer? comp2 : comp1;
    const float* V    = layer? V2    : V1;
    ushortT* Wt       = layer? Wt2   : Wt1;
    int o  = t >> 10;                // 0..127
    int rk = t & 1023;
    int r  = rk >> 7, k = rk & 127;
    float s=0.f;
    #pragma unroll
    for(int b=0;b<NREL;b++) s += comp[r*NREL+b]*V[(b<<14) + k*HD + o];
    Wt[t]=f2b(s);
  }
}

__global__ void k_scan1(const int* __restrict__ in, int* __restrict__ out,
                        int* __restrict__ part, int n){
  __shared__ int sm[256];
  int t = threadIdx.x; int i = blockIdx.x*256+t;
  int v = (i<n)? in[i] : 0;
  sm[t]=v; __syncthreads();
  for(int off=1; off<256; off<<=1){
    int x = (t>=off)? sm[t-off] : 0;
    __syncthreads();
    sm[t]+=x;
    __syncthreads();
  }
  if(i<n) out[i]=sm[t]-v;       // exclusive within block
  if(t==255) part[blockIdx.x]=sm[255];
}

// single-block chunked scan of the partials
__global__ void k_scanmid(int* __restrict__ part, int n){
  __shared__ int sm[256];
  __shared__ int carry;
  int t=threadIdx.x;
  if(t==0) carry=0;
  __syncthreads();
  for(int base=0; base<n; base+=256){
    int i=base+t;
    int v=(i<n)? part[i] : 0;
    sm[t]=v; __syncthreads();
    for(int off=1; off<256; off<<=1){
      int x=(t>=off)? sm[t-off] : 0;
      __syncthreads();
      sm[t]+=x;
      __syncthreads();
    }
    int tot = sm[255];
    if(i<n) part[i]=sm[t]-v+carry;
    __syncthreads();
    if(t==0) carry += tot;
    __syncthreads();
  }
}

// finalize absolute bucket offsets (+sentinel) so consumers do ONE metadata load
__global__ void k_fin(const int* __restrict__ offs, const int* __restrict__ part,
                      int* __restrict__ offs_full){
  int i = blockIdx.x*blockDim.x + threadIdx.x;
  if(i < NBUCK) offs_full[i] = offs[i] + part[i>>8];
  else if(i == NBUCK) offs_full[i] = N_EDGES;
}

// edge record: src in low 16 bits, fp16 weight in high 16 bits (4B total)
__global__ void k_scatter(const int* __restrict__ src, const int* __restrict__ et,
                          const float* __restrict__ w, const int* __restrict__ dst,
                          const int* __restrict__ offs_full, const int* __restrict__ pos,
                          uint32_t* __restrict__ es){
  int i = blockIdx.x*blockDim.x + threadIdx.x;
  if(i<N_EDGES){
    int b = dst[i]*NREL + et[i];
    __half h = __float2half(w[i]);
    ushortT hb; __builtin_memcpy(&hb,&h,2);
    es[offs_full[b] + pos[i]] = (uint32_t)(src[i] & 0xFFFF) | ((uint32_t)hb << 16);
  }
}

// ---------------- aggregate-first: 4 buckets per WAVE ----------------
// lane = q*16+f : quarter q owns bucket wave*4+q, lane f covers bytes [f*16,f*16+16)
// Acat[b][128] bf16, b = node*8+r  (== A[node][1024] r-major)
__global__ void __launch_bounds__(256)
k_agg(const ushortT* __restrict__ xb,   // [N][128] bf16 gather table
      const int* __restrict__ offs_full,
      const uint32_t* __restrict__ es,  // packed (src u16, w fp16)
      ushortT* __restrict__ Acat){
  int wave = blockIdx.x*4 + (threadIdx.x>>6);
  int lane = threadIdx.x & 63;
  int q = lane >> 4, f = lane & 15;
  int b = wave*4 + q;                   // grid sized exactly: NBUCK/4 waves
  int beg = offs_full[b], cnt = offs_full[b+1] - beg;
  const uint32_t* ep = es + beg;
  float a[8] = {};
  uint32_t e = 0;
  if(cnt > 0) e = ep[0];                // masked prefetch
  for(int j=0;j<cnt;j++){
    uint32_t ce = e;
    if(j+1 < cnt) e = ep[j+1];          // prefetch next edge while gathering
    ushortT hb = (ushortT)(ce >> 16);
    __half h; __builtin_memcpy(&h,&hb,2);
    float w = __half2float(h);
    int s = (int)(ce & 0xFFFFu);
    bf16x8 v = *(const bf16x8*)&xb[(size_t)s*HD + f*8];
    #pragma unroll
    for(int t=0;t<8;t++) a[t] += w * b2f((uint16_t)v[t]);
  }
  uint32_t pk[4];
  #pragma unroll
  for(int i=0;i<4;i++)
    pk[i] = (uint32_t)f2b(a[2*i]) | ((uint32_t)f2b(a[2*i+1])<<16);
  // wave writes 4 adjacent 256B rows -> 1KB contiguous
  *(uint4*)&Acat[(size_t)b*HD + f*8] = *(uint4*)pk;
}

// ---------------- MFMA GEMM (round-5 proven): out[M][128] = A[M][1024] @ Wt^T --
constexpr int BM=64, BN=128, BK=64, LDKG=72;   // pad: 144B row, 2-way alias (free)
__global__ void __launch_bounds__(256)
k_gemm(const ushortT* __restrict__ A,   // [M][1024] bf16
       const ushortT* __restrict__ Wt,  // [128][1024] bf16 (B^T, o-major)
       const float* __restrict__ bias,
       float* __restrict__ outF,        // layer2 output (f32) or null
       ushortT* __restrict__ outB,      // layer1 output (bf16) or null
       int M, int relu){
  __shared__ ushortT Asm[BM][LDKG];
  __shared__ ushortT Bsm[BN][LDKG];
  int tid = threadIdx.x;
  int wid = tid>>6, lane = tid&63;
  int l15 = lane&15, lhi = lane>>4;
  int row0 = blockIdx.x*BM;
  int wr = (wid>>1)*32, wc = (wid&1)*64;   // wave tile 32x64
  f32x4 acc[2][4] = {};
  for(int kt=0; kt<NREL*HD; kt+=BK){
    #pragma unroll
    for(int q=0;q<2;q++){
      int slot = q*256 + tid;
      int r = slot>>3, kb8 = (slot&7)*8;
      int grow = row0 + r; if(grow >= M) grow = M-1;
      *(bf16x8*)&Asm[r][kb8] = *(const bf16x8*)&A[(size_t)grow*1024 + kt + kb8];
    }
    #pragma unroll
    for(int q=0;q<4;q++){
      int slot = q*256 + tid;
      int c = slot>>3, kb8 = (slot&7)*8;
      *(bf16x8*)&Bsm[c][kb8] = *(const bf16x8*)&Wt[(size_t)c*1024 + kt + kb8];
    }
    __syncthreads();
    #pragma unroll
    for(int kk=0;kk<2;kk++){
      bf16x8 af[2], bfr[4];
      #pragma unroll
      for(int m=0;m<2;m++)  af[m]  = *(const bf16x8*)&Asm[wr + m*16 + l15][kk*32 + lhi*8];
      #pragma unroll
      for(int n=0;n<4;n++)  bfr[n] = *(const bf16x8*)&Bsm[wc + n*16 + l15][kk*32 + lhi*8];
      #pragma unroll
      for(int m=0;m<2;m++)
        #pragma unroll
        for(int n=0;n<4;n++)
          acc[m][n] = __builtin_amdgcn_mfma_f32_16x16x32_bf16(af[m], bfr[n], acc[m][n], 0,0,0);
    }
    __syncthreads();
  }
  #pragma unroll
  for(int m=0;m<2;m++){
    #pragma unroll
    for(int j=0;j<4;j++){
      int grow = row0 + wr + m*16 + lhi*4 + j;
      if(grow < M){
        #pragma unroll
        for(int n=0;n<4;n++){
          int col = wc + n*16 + l15;
          float v = acc[m][n][j] + bias[col];
          if(relu) v = fmaxf(v, 0.f);
          if(outF) outF[(size_t)grow*HD + col] = v;
          else     outB[(size_t)grow*HD + col] = f2b(v);
        }
      }
    }
  }
}

extern "C" void kernel_launch(void* const* d_in, const int* in_sizes, int n_in,
                              void* d_out, int out_size, void* d_ws, size_t ws_size,
                              hipStream_t stream){
  const float* feat  = (const float*)d_in[0];
  const int*   etyp  = (const int*)  d_in[1];
  const float* ew    = (const float*)d_in[2];
  const int*   src   = (const int*)  d_in[3];
  const int*   dst   = (const int*)  d_in[4];
  const float* comp1 = (const float*)d_in[5];
  const float* V1    = (const float*)d_in[6];
  const float* bias1 = (const float*)d_in[7];
  const float* comp2 = (const float*)d_in[8];
  const float* V2    = (const float*)d_in[9];
  const float* bias2 = (const float*)d_in[10];
  float* out = (float*)d_out;

  char* p = (char*)d_ws;
  auto alloc = [&](size_t bytes)->char* {
    char* q = p; p += (bytes + 255) & ~(size_t)255; return q;
  };
  ushortT* Wt1   = (ushortT*)alloc((size_t)HD*NREL*HD*2);        // 256 KB
  ushortT* Wt2   = (ushortT*)alloc((size_t)HD*NREL*HD*2);        // 256 KB
  ushortT* Acat  = (ushortT*)alloc((size_t)NBUCK*HD*2);          // 102.4 MB
  ushortT* xb    = (ushortT*)alloc((size_t)N_NODES*HD*2);        // 12.8 MB
  ushortT* hmid  = (ushortT*)alloc((size_t)N_NODES*HD*2);        // 12.8 MB
  int*   deg   = (int*)  alloc((size_t)NBUCK*4);
  int*   offs  = (int*)  alloc((size_t)NBUCK*4);
  int*   offsF = (int*)  alloc((size_t)(NBUCK+1)*4);
  int*   part1 = (int*)  alloc(2048*4);
  int*   pos   = (int*)  alloc((size_t)N_EDGES*4);               // 3.2 MB
  uint32_t* es = (uint32_t*)alloc((size_t)N_EDGES*4);            // 3.2 MB

  // ---- CSR build over 400k (dst,etype) buckets ----
  hipMemsetAsync(deg, 0, (size_t)NBUCK*4, stream);
  // hist(+pos) | f2b | relw fused
  k_histprep<<<H_BLOCKS + F2B_BLOCKS + 1024, 256, 0, stream>>>(
      dst,etyp,deg,pos, feat, comp1,V1,comp2,V2, xb, Wt1,Wt2);
  int nb1 = (NBUCK+255)/256;          // 1563
  k_scan1<<<nb1,256,0,stream>>>(deg,offs,part1,NBUCK);
  k_scanmid<<<1,256,0,stream>>>(part1,nb1);
  k_fin<<<(NBUCK+256)/256 + 1,256,0,stream>>>(offs,part1,offsF);
  k_scatter<<<H_BLOCKS,256,0,stream>>>(src,etyp,ew,dst,offsF,pos,es);

  int aggGrid  = NBUCK/16;                 // 25000 blocks: 4 waves x 4 buckets
  int gemmGrid = (N_NODES + BM - 1)/BM;    // 782
  // ---- layer 1 ----
  k_agg<<<aggGrid,256,0,stream>>>(xb,   offsF, es, Acat);
  k_gemm<<<gemmGrid,256,0,stream>>>(Acat, Wt1, bias1, nullptr, hmid, N_NODES, 1);
  // ---- layer 2 ----
  k_agg<<<aggGrid,256,0,stream>>>(hmid, offsF, es, Acat);
  k_gemm<<<gemmGrid,256,0,stream>>>(Acat, Wt2, bias2, out, nullptr, N_NODES, 0);
}

// Round 14
// 237.997 us; speedup vs baseline: 1.6250x; 1.0189x over previous
//
#include <hip/hip_runtime.h>
#include <hip/hip_fp16.h>
#include <stdint.h>

constexpr int N_NODES = 50000;
constexpr int N_EDGES = 800000;
constexpr int HD      = 128;
constexpr int NREL    = 8;
constexpr int NBUCK   = N_NODES * NREL;   // 400000 (dst,etype) buckets

typedef unsigned short ushortT;
using bf16x8 = __attribute__((ext_vector_type(8))) short;
using f32x4  = __attribute__((ext_vector_type(4))) float;

__device__ __forceinline__ float b2f(uint32_t lo16){
  uint32_t x = lo16 << 16; float f; __builtin_memcpy(&f,&x,4); return f;
}
__device__ __forceinline__ uint16_t f2b(float f){
  uint32_t x; __builtin_memcpy(&x,&f,4);
  uint32_t r = (x + 0x7FFFu + ((x>>16)&1u)) >> 16;
  return (uint16_t)r;
}

// ---------------- fused: histogram(+position, 4-edge MLP) | f2b | relw -----
constexpr int H4_BLOCKS  = (N_EDGES + 1023)/1024;      // 782 (4 edges/thread)
constexpr int F2B_BLOCKS = (N_NODES*HD/4 + 255)/256;   // 6250
__global__ void k_histprep(const int* __restrict__ dst, const int* __restrict__ et,
                           int* __restrict__ deg, int* __restrict__ pos,
                           const float* __restrict__ feat,
                           const float* __restrict__ comp1, const float* __restrict__ V1,
                           const float* __restrict__ comp2, const float* __restrict__ V2,
                           ushortT* __restrict__ xb,
                           ushortT* __restrict__ Wt1, ushortT* __restrict__ Wt2){
  if(blockIdx.x < H4_BLOCKS){
    int base = blockIdx.x*1024 + threadIdx.x;
    #pragma unroll
    for(int u=0;u<4;u++){
      int i = base + u*256;               // 4 independent atomics in flight
      if(i<N_EDGES) pos[i] = atomicAdd(&deg[dst[i]*NREL + et[i]],1);
    }
  } else if(blockIdx.x < H4_BLOCKS + F2B_BLOCKS){
    int i = (blockIdx.x - H4_BLOCKS)*256 + threadIdx.x;
    if(i < N_NODES*HD/4){
      float4 v = ((const float4*)feat)[i];
      ushort4 o;
      o.x=f2b(v.x); o.y=f2b(v.y); o.z=f2b(v.z); o.w=f2b(v.w);
      ((ushort4*)xb)[i]=o;
    }
  } else {
    int t = (blockIdx.x - H4_BLOCKS - F2B_BLOCKS)*256 + threadIdx.x; // 0..262143
    int layer = t >> 17;
    t &= 131071;
    const float* comp = layer? comp2 : comp1;
    const float* V    = layer? V2    : V1;
    ushortT* Wt       = layer? Wt2   : Wt1;
    int o  = t >> 10;                // 0..127
    int rk = t & 1023;
    int r  = rk >> 7, k = rk & 127;
    float s=0.f;
    #pragma unroll
    for(int b=0;b<NREL;b++) s += comp[r*NREL+b]*V[(b<<14) + k*HD + o];
    Wt[t]=f2b(s);
  }
}

// 1024-thread scan blocks: 391 blocks over 400k
__global__ void k_scan1(const int* __restrict__ in, int* __restrict__ out,
                        int* __restrict__ part, int n){
  __shared__ int sm[1024];
  int t = threadIdx.x; int i = blockIdx.x*1024+t;
  int v = (i<n)? in[i] : 0;
  sm[t]=v; __syncthreads();
  for(int off=1; off<1024; off<<=1){
    int x = (t>=off)? sm[t-off] : 0;
    __syncthreads();
    sm[t]+=x;
    __syncthreads();
  }
  if(i<n) out[i]=sm[t]-v;       // exclusive within block
  if(t==1023) part[blockIdx.x]=sm[1023];
}

// single-block scan of the 391 partials (512 threads)
__global__ void k_scanmid(int* __restrict__ part, int n){
  __shared__ int sm[512];
  __shared__ int carry;
  int t=threadIdx.x;
  if(t==0) carry=0;
  __syncthreads();
  for(int base=0; base<n; base+=512){
    int i=base+t;
    int v=(i<n)? part[i] : 0;
    sm[t]=v; __syncthreads();
    for(int off=1; off<512; off<<=1){
      int x=(t>=off)? sm[t-off] : 0;
      __syncthreads();
      sm[t]+=x;
      __syncthreads();
    }
    int tot = sm[511];
    if(i<n) part[i]=sm[t]-v+carry;
    __syncthreads();
    if(t==0) carry += tot;
    __syncthreads();
  }
}

// finalize absolute bucket offsets (+sentinel): one metadata load for consumers
__global__ void k_fin(const int* __restrict__ offs, const int* __restrict__ part,
                      int* __restrict__ offs_full){
  int i = blockIdx.x*blockDim.x + threadIdx.x;
  if(i < NBUCK) offs_full[i] = offs[i] + part[i>>10];
  else if(i == NBUCK) offs_full[i] = N_EDGES;
}

// edge record: src in low 16 bits, fp16 weight in high 16 bits (4B total)
__global__ void k_scatter(const int* __restrict__ src, const int* __restrict__ et,
                          const float* __restrict__ w, const int* __restrict__ dst,
                          const int* __restrict__ offs_full, const int* __restrict__ pos,
                          uint32_t* __restrict__ es){
  int i = blockIdx.x*blockDim.x + threadIdx.x;
  if(i<N_EDGES){
    int b = dst[i]*NREL + et[i];
    __half h = __float2half(w[i]);
    ushortT hb; __builtin_memcpy(&hb,&h,2);
    es[offs_full[b] + pos[i]] = (uint32_t)(src[i] & 0xFFFF) | ((uint32_t)hb << 16);
  }
}

// ---------------- aggregate-first: 4 buckets per WAVE, pipelined gather -----
// lane = q*16+f : quarter q owns bucket wave*4+q, lane f covers bytes [f*16,f*16+16)
// Acat[b][128] bf16, b = node*8+r  (== A[node][1024] r-major)
__global__ void __launch_bounds__(256)
k_agg(const ushortT* __restrict__ xb,   // [N][128] bf16 gather table
      const int* __restrict__ offs_full,
      const uint32_t* __restrict__ es,  // packed (src u16, w fp16)
      ushortT* __restrict__ Acat){
  int wave = blockIdx.x*4 + (threadIdx.x>>6);
  int lane = threadIdx.x & 63;
  int q = lane >> 4, f = lane & 15;
  int b = wave*4 + q;                   // grid sized exactly: NBUCK/4 waves
  int beg = offs_full[b], cnt = offs_full[b+1] - beg;
  const uint32_t* ep = es + beg;
  float a[8] = {};
  uint32_t e0 = 0, e1 = 0;
  bf16x8 v0 = {};
  if(cnt > 0){
    e0 = ep[0];
    v0 = *(const bf16x8*)&xb[(size_t)(e0 & 0xFFFFu)*HD + f*8];   // gather 0 in flight
    if(cnt > 1) e1 = ep[1];
  }
  for(int j=0;j<cnt;j++){
    bf16x8 v1 = {};
    if(j+1 < cnt)                       // issue NEXT gather before consuming v0
      v1 = *(const bf16x8*)&xb[(size_t)(e1 & 0xFFFFu)*HD + f*8];
    uint32_t e2 = (j+2 < cnt)? ep[j+2] : 0;   // prefetch es two ahead
    ushortT hb = (ushortT)(e0 >> 16);
    __half h; __builtin_memcpy(&h,&hb,2);
    float w = __half2float(h);
    #pragma unroll
    for(int t=0;t<8;t++) a[t] += w * b2f((uint16_t)v0[t]);   // waits on v0 only
    e0 = e1; e1 = e2; v0 = v1;
  }
  uint32_t pk[4];
  #pragma unroll
  for(int i=0;i<4;i++)
    pk[i] = (uint32_t)f2b(a[2*i]) | ((uint32_t)f2b(a[2*i+1])<<16);
  // wave writes 4 adjacent 256B rows -> 1KB contiguous
  *(uint4*)&Acat[(size_t)b*HD + f*8] = *(uint4*)pk;
}

// ---------------- MFMA GEMM (round-5 proven): out[M][128] = A[M][1024] @ Wt^T --
constexpr int BM=64, BN=128, BK=64, LDKG=72;   // pad: 144B row, 2-way alias (free)
__global__ void __launch_bounds__(256)
k_gemm(const ushortT* __restrict__ A,   // [M][1024] bf16
       const ushortT* __restrict__ Wt,  // [128][1024] bf16 (B^T, o-major)
       const float* __restrict__ bias,
       float* __restrict__ outF,        // layer2 output (f32) or null
       ushortT* __restrict__ outB,      // layer1 output (bf16) or null
       int M, int relu){
  __shared__ ushortT Asm[BM][LDKG];
  __shared__ ushortT Bsm[BN][LDKG];
  int tid = threadIdx.x;
  int wid = tid>>6, lane = tid&63;
  int l15 = lane&15, lhi = lane>>4;
  int row0 = blockIdx.x*BM;
  int wr = (wid>>1)*32, wc = (wid&1)*64;   // wave tile 32x64
  f32x4 acc[2][4] = {};
  for(int kt=0; kt<NREL*HD; kt+=BK){
    #pragma unroll
    for(int q=0;q<2;q++){
      int slot = q*256 + tid;
      int r = slot>>3, kb8 = (slot&7)*8;
      int grow = row0 + r; if(grow >= M) grow = M-1;
      *(bf16x8*)&Asm[r][kb8] = *(const bf16x8*)&A[(size_t)grow*1024 + kt + kb8];
    }
    #pragma unroll
    for(int q=0;q<4;q++){
      int slot = q*256 + tid;
      int c = slot>>3, kb8 = (slot&7)*8;
      *(bf16x8*)&Bsm[c][kb8] = *(const bf16x8*)&Wt[(size_t)c*1024 + kt + kb8];
    }
    __syncthreads();
    #pragma unroll
    for(int kk=0;kk<2;kk++){
      bf16x8 af[2], bfr[4];
      #pragma unroll
      for(int m=0;m<2;m++)  af[m]  = *(const bf16x8*)&Asm[wr + m*16 + l15][kk*32 + lhi*8];
      #pragma unroll
      for(int n=0;n<4;n++)  bfr[n] = *(const bf16x8*)&Bsm[wc + n*16 + l15][kk*32 + lhi*8];
      #pragma unroll
      for(int m=0;m<2;m++)
        #pragma unroll
        for(int n=0;n<4;n++)
          acc[m][n] = __builtin_amdgcn_mfma_f32_16x16x32_bf16(af[m], bfr[n], acc[m][n], 0,0,0);
    }
    __syncthreads();
  }
  #pragma unroll
  for(int m=0;m<2;m++){
    #pragma unroll
    for(int j=0;j<4;j++){
      int grow = row0 + wr + m*16 + lhi*4 + j;
      if(grow < M){
        #pragma unroll
        for(int n=0;n<4;n++){
          int col = wc + n*16 + l15;
          float v = acc[m][n][j] + bias[col];
          if(relu) v = fmaxf(v, 0.f);
          if(outF) outF[(size_t)grow*HD + col] = v;
          else     outB[(size_t)grow*HD + col] = f2b(v);
        }
      }
    }
  }
}

extern "C" void kernel_launch(void* const* d_in, const int* in_sizes, int n_in,
                              void* d_out, int out_size, void* d_ws, size_t ws_size,
                              hipStream_t stream){
  const float* feat  = (const float*)d_in[0];
  const int*   etyp  = (const int*)  d_in[1];
  const float* ew    = (const float*)d_in[2];
  const int*   src   = (const int*)  d_in[3];
  const int*   dst   = (const int*)  d_in[4];
  const float* comp1 = (const float*)d_in[5];
  const float* V1    = (const float*)d_in[6];
  const float* bias1 = (const float*)d_in[7];
  const float* comp2 = (const float*)d_in[8];
  const float* V2    = (const float*)d_in[9];
  const float* bias2 = (const float*)d_in[10];
  float* out = (float*)d_out;

  char* p = (char*)d_ws;
  auto alloc = [&](size_t bytes)->char* {
    char* q = p; p += (bytes + 255) & ~(size_t)255; return q;
  };
  ushortT* Wt1   = (ushortT*)alloc((size_t)HD*NREL*HD*2);        // 256 KB
  ushortT* Wt2   = (ushortT*)alloc((size_t)HD*NREL*HD*2);        // 256 KB
  ushortT* Acat  = (ushortT*)alloc((size_t)NBUCK*HD*2);          // 102.4 MB
  ushortT* xb    = (ushortT*)alloc((size_t)N_NODES*HD*2);        // 12.8 MB
  ushortT* hmid  = (ushortT*)alloc((size_t)N_NODES*HD*2);        // 12.8 MB
  int*   deg   = (int*)  alloc((size_t)NBUCK*4);
  int*   offs  = (int*)  alloc((size_t)NBUCK*4);
  int*   offsF = (int*)  alloc((size_t)(NBUCK+1)*4);
  int*   part1 = (int*)  alloc(2048*4);
  int*   pos   = (int*)  alloc((size_t)N_EDGES*4);               // 3.2 MB
  uint32_t* es = (uint32_t*)alloc((size_t)N_EDGES*4);            // 3.2 MB

  // ---- CSR build over 400k (dst,etype) buckets ----
  (void)hipMemsetAsync(deg, 0, (size_t)NBUCK*4, stream);
  // hist(+pos, 4-edge MLP) | f2b | relw fused
  k_histprep<<<H4_BLOCKS + F2B_BLOCKS + 1024, 256, 0, stream>>>(
      dst,etyp,deg,pos, feat, comp1,V1,comp2,V2, xb, Wt1,Wt2);
  int nb1 = (NBUCK+1023)/1024;        // 391
  k_scan1<<<nb1,1024,0,stream>>>(deg,offs,part1,NBUCK);
  k_scanmid<<<1,512,0,stream>>>(part1,nb1);
  k_fin<<<(NBUCK+256)/256 + 1,256,0,stream>>>(offs,part1,offsF);
  k_scatter<<<(N_EDGES+255)/256,256,0,stream>>>(src,etyp,ew,dst,offsF,pos,es);

  int aggGrid  = NBUCK/16;                 // 25000 blocks: 4 waves x 4 buckets
  int gemmGrid = (N_NODES + BM - 1)/BM;    // 782
  // ---- layer 1 ----
  k_agg<<<aggGrid,256,0,stream>>>(xb,   offsF, es, Acat);
  k_gemm<<<gemmGrid,256,0,stream>>>(Acat, Wt1, bias1, nullptr, hmid, N_NODES, 1);
  // ---- layer 2 ----
  k_agg<<<aggGrid,256,0,stream>>>(hmid, offsF, es, Acat);
  k_gemm<<<gemmGrid,256,0,stream>>>(Acat, Wt2, bias2, out, nullptr, N_NODES, 0);
}